// Round 6
// baseline (5318.906 us; speedup 1.0000x reference)
//
#include <hip/hip_runtime.h>
#include <hip/hip_bf16.h>
#include <hip/hip_fp8.h>
#include <math.h>

// Encoder GRU, B=8192 T=256 H=512 — sync-free state-resident, v9.
// v8 (flags instead of barrier, HW fp8 cvt, dbuf state, paired dwordx4 B
// loads, setprio) + DEPTH-4 B prefetch: 4 static slots S[0..3], 4-phase
// body (kc+=4, unroll 1). Phase j: spin flag -> ds_read A -> MFMA S[j] ->
// refill S[j] with phase (kc+j+4)&15 (wraps into next step; 12 loads fly
// through the epilogue). Rationale: v8 counters show MFMA pipe ~92%-sat
// during its window but the B-stream runs at only ~69 GB/s/CU (bytes-in-
// flight limited: ping-pong drains to ~3 outstanding loads). Depth-4 keeps
// 9-12 loads (144-192 B/wave) in flight -> ~2x per-CU L2 rate.
// Slot indices are compile-time (v4's spill trap was full-unroll + modulo
// ring); live-range delta is +24 VGPR.
// d_in: x(B,T), kmforenc(T), dense_kernel(1,H), dense_bias(H),
//       gru_kernel(H,3H), gru_recurrent(H,3H), gru_bias(2,3H)

constexpr int B_  = 8192;
constexpr int T_  = 256;
constexpr int H_  = 512;
constexpr int H3_ = 1536;
constexpr size_t BH = (size_t)B_ * H_;
constexpr int ROWS = 32;

typedef float f32x4 __attribute__((ext_vector_type(4)));
typedef long  lx2   __attribute__((ext_vector_type(2)));

__device__ __forceinline__ unsigned char f2e4m3(float f) {
    __hip_fp8_e4m3 v(f); return v.__x;
}
// swizzled byte offset into one fp8 state plane [32 rows][512 cols]
__device__ __forceinline__ int swz(int row, int col) {
    return (row * 512 + col) ^ ((row & 15) << 3);
}
__device__ __forceinline__ float fast_sigmoid(float v) {
    return __builtin_amdgcn_rcpf(1.f + __expf(-v));
}
__device__ __forceinline__ float fast_tanh(float v) {
    float a = fabsf(v);
    float e = __expf(-2.f * a);
    float t = (1.f - e) * __builtin_amdgcn_rcpf(1.f + e);
    return copysignf(t, v);
}

// wx[j] = sum_h dense_kernel[h]*gru_kernel[h,j]
// cc[j] = sum_h dense_bias[h]*gru_kernel[h,j] + gru_bias[0][j]
__global__ void prep_wx(const float* __restrict__ dk,
                        const float* __restrict__ db,
                        const float* __restrict__ K,
                        const float* __restrict__ gb,
                        float* __restrict__ wx,
                        float* __restrict__ cc) {
    int j = blockIdx.x * blockDim.x + threadIdx.x;
    if (j >= H3_) return;
    float a = 0.f, c = 0.f;
    for (int h = 0; h < H_; ++h) {
        float kv = K[(size_t)h * H3_ + j];
        a = fmaf(dk[h], kv, a);
        c = fmaf(db[h], kv, c);
    }
    wx[j] = a;
    cc[j] = c + gb[j];
}

// Pack R (H x 3H row-major) into per-(kc,w) fragment-PAIR blocks so one
// dwordx4 per lane fetches two MFMA B fragments:
//   pair block (kc,w,p): 128 ulongs; lane L holds ulongs [2L, 2L+1] =
//   frag f=2p and f=2p+1 lane-L data.
//   frag f: n = g*512 + w*32 + q*16 + (lane&15), k = kc*32 + 8*(lane>>4)+e,
//   with g=f>>1, q=f&1 (p==g, j==q).
__global__ void pack_Rf8(const float* __restrict__ R,
                         unsigned long long* __restrict__ Rp) {
    int idx  = blockIdx.x * 256 + threadIdx.x;    // < 98304
    int lane = idx & 63;
    int fi   = idx >> 6;                          // 0..1535
    int f    = fi % 6;
    int rest = fi / 6;                            // kc*16 + w
    int g    = f >> 1, q = f & 1;
    int w    = rest & 15;
    int n    = g * 512 + w * 32 + q * 16 + (lane & 15);
    int kb   = (rest >> 4) * 32 + 8 * (lane >> 4);
    unsigned long long v = 0;
    #pragma unroll
    for (int e = 0; e < 8; ++e)
        v |= (unsigned long long)f2e4m3(R[(size_t)(kb + e) * H3_ + n]) << (8 * e);
    Rp[(size_t)(rest * 3 + g) * 128 + 2 * lane + q] = v;
}

__global__ __launch_bounds__(1024, 4) void gru_f8(
    const float* __restrict__ x, const float* __restrict__ km,
    const unsigned long long* __restrict__ Rp,
    const float* __restrict__ wx, const float* __restrict__ cc,
    const float* __restrict__ b1,
    float* __restrict__ out0, float* __restrict__ out1)
{
    __shared__ __align__(16) unsigned char st[2][ROWS * 512]; // dbuf fp8 state
    __shared__ float rkm[T_];
    __shared__ int flags[16];                     // steps completed per wave

    const int tid  = threadIdx.x;
    const int lane = tid & 63;
    const int w    = tid >> 6;                    // wave 0..15 -> cols [w*32,+32)
    const int l15  = lane & 15;
    const int lh   = lane >> 4;                   // 0..3
    const int row0 = blockIdx.x * ROWS;
    const bool odd1 = (l15 & 1) != 0;
    const bool odd2 = (l15 & 2) != 0;
    volatile int* vflag = (volatile int*)flags;

    if (tid < T_) rkm[tid] = 1.f / km[tid];
    if (tid < 16) flags[tid] = 0;

    // per-thread gate constants (loop-invariant)
    const int jcq[2] = { w * 32 + l15, w * 32 + 16 + l15 };
    float wxz[2], wxr[2], wxh[2], czc[2], crc[2], cch[2], b1h[2];
    #pragma unroll
    for (int q = 0; q < 2; ++q) {
        int jc = jcq[q];
        wxz[q] = wx[jc];  wxr[q] = wx[512 + jc];  wxh[q] = wx[1024 + jc];
        czc[q] = cc[jc]        + b1[jc];
        crc[q] = cc[512 + jc]  + b1[512 + jc];
        cch[q] = cc[1024 + jc];
        b1h[q] = b1[1024 + jc];
    }

    float hprev[2][2][4];                         // [q][mi][rr] fp32 carry
    #pragma unroll
    for (int q = 0; q < 2; ++q)
        #pragma unroll
        for (int mi = 0; mi < 2; ++mi)
            #pragma unroll
            for (int rr = 0; rr < 4; ++rr) hprev[q][mi][rr] = 0.f;

    // B stream: pair block stride 128 ulongs, kc stride 16*3*128 = 6144
    const unsigned long long* wb = Rp + (size_t)w * 384 + 2 * lane;

    __syncthreads();   // rkm + flags init visible (only barrier in kernel)

    // depth-4 slots: S[j] holds phase (kc: last refill) data; entering each
    // step S[0..3] hold kc=0..3 (prologue or previous step's wrap refills).
    lx2 S[4][3];
    #pragma unroll
    for (int j = 0; j < 4; ++j)
        #pragma unroll
        for (int p = 0; p < 3; ++p)
            S[j][p] = *(const lx2*)(wb + (size_t)j * 6144 + p * 128);

    #pragma unroll 1
    for (int t = 0; t < T_; ++t) {
        const char* rd = (const char*)st[t & 1];           // old state
        char*       wr = (char*)st[(t & 1) ^ 1];           // new state

        f32x4 acc[6][2];
        #pragma unroll
        for (int f = 0; f < 6; ++f) {
            acc[f][0] = (f32x4){0.f, 0.f, 0.f, 0.f};
            acc[f][1] = (f32x4){0.f, 0.f, 0.f, 0.f};
        }

        if (t > 0) {
            #pragma unroll 1
            for (int kc = 0; kc < 16; kc += 4) {
                #pragma unroll
                for (int j = 0; j < 4; ++j) {
                    const int ph = kc + j;
                    // wait for producer wave ph's step t-1 epilogue
                    while (vflag[ph] < t) __builtin_amdgcn_s_sleep(1);
                    asm volatile("" ::: "memory");
                    long A0 = *(const long*)(rd + swz(l15,      ph * 32 + lh * 8));
                    long A1 = *(const long*)(rd + swz(l15 + 16, ph * 32 + lh * 8));
                    __builtin_amdgcn_s_setprio(1);
                    #pragma unroll
                    for (int p = 0; p < 3; ++p) {
                        #pragma unroll
                        for (int jj = 0; jj < 2; ++jj) {
                            const int f = 2 * p + jj;
                            acc[f][0] = __builtin_amdgcn_mfma_f32_16x16x32_fp8_fp8(
                                A0, S[j][p][jj], acc[f][0], 0, 0, 0);
                            acc[f][1] = __builtin_amdgcn_mfma_f32_16x16x32_fp8_fp8(
                                A1, S[j][p][jj], acc[f][1], 0, 0, 0);
                        }
                    }
                    __builtin_amdgcn_s_setprio(0);
                    // refill slot j for phase ph+4 (wraps into next step's
                    // kc=j at ph>=12 — those 12 loads fly through epilogue)
                    #pragma unroll
                    for (int p = 0; p < 3; ++p)
                        S[j][p] = *(const lx2*)(wb
                            + (size_t)((ph + 4) & 15) * 6144 + p * 128);
                }
            }
        }

        // gates + state update; reads old plane (rd), writes new plane (wr).
        const float rk = rkm[t];
        #pragma unroll
        for (int mi = 0; mi < 2; ++mi) {
            #pragma unroll
            for (int rr = 0; rr < 4; ++rr) {
                const int brow = mi * 16 + lh * 4 + rr;
                const float cb = ((t == 0)
                    ? x[(size_t)(row0 + brow) * T_]
                    : __builtin_amdgcn_cvt_f32_fp8(
                          (int)((const unsigned char*)rd)[swz(brow, t)], 0)) * rk;
                #pragma unroll
                for (int q = 0; q < 2; ++q) {
                    float z   = fast_sigmoid(fmaf(cb, wxz[q], czc[q])
                                             + acc[q][mi][rr]);
                    float r   = fast_sigmoid(fmaf(cb, wxr[q], crc[q])
                                             + acc[2 + q][mi][rr]);
                    float mhh = acc[4 + q][mi][rr] + b1h[q];
                    float hh  = fast_tanh(fmaf(r, mhh, fmaf(cb, wxh[q], cch[q])));
                    float hn  = fmaf(z, hprev[q][mi][rr] - hh, hh);
                    hprev[q][mi][rr] = hn;
                    // pack 4 consecutive cols (across l15 quads) into one dword:
                    // DPP xor1 swap -> HW cvt_pk (ordered pair) -> xor2 merge.
                    float nb = __shfl_xor(hn, 1);
                    float lo = odd1 ? nb : hn;
                    float hi = odd1 ? hn : nb;
                    unsigned int w16 = (unsigned int)
                        __builtin_amdgcn_cvt_pk_fp8_f32(lo, hi, 0, false);
                    unsigned int v16 = (unsigned int)__shfl_xor((int)w16, 2);
                    unsigned int w32 = (odd2 ? v16 : w16)
                                     | ((odd2 ? w16 : v16) << 16);
                    if ((l15 & 3) == 0)
                        *(unsigned int*)(wr + swz(brow, w * 32 + q * 16 + l15)) = w32;
                }
            }
        }

        // publish: all this wave's LDS reads (phases + colb) and writes done,
        // then raise flag. Consumers spin on it; no block barrier.
        asm volatile("s_waitcnt lgkmcnt(0)" ::: "memory");
        if (lane == 0) vflag[w] = t + 1;
    }

    // final state from fp32 register carry -> both output halves
    #pragma unroll
    for (int q = 0; q < 2; ++q)
        #pragma unroll
        for (int mi = 0; mi < 2; ++mi)
            #pragma unroll
            for (int rr = 0; rr < 4; ++rr) {
                int brow = mi * 16 + lh * 4 + rr;
                size_t o = (size_t)(row0 + brow) * H_ + jcq[q];
                float v = hprev[q][mi][rr];
                out0[o] = v;
                out1[o] = v;
            }
}

extern "C" void kernel_launch(void* const* d_in, const int* in_sizes, int n_in,
                              void* d_out, int out_size, void* d_ws, size_t ws_size,
                              hipStream_t stream) {
    const float* x  = (const float*)d_in[0];
    const float* km = (const float*)d_in[1];
    const float* dk = (const float*)d_in[2];
    const float* db = (const float*)d_in[3];
    const float* K  = (const float*)d_in[4];
    const float* R  = (const float*)d_in[5];
    const float* gb = (const float*)d_in[6];

    float* out  = (float*)d_out;
    float* out1 = out + BH;

    float* wx = (float*)d_ws;                     // 1536 f
    float* cc = wx + H3_;                         // 1536 f
    unsigned long long* Rp = (unsigned long long*)(cc + H3_);   // 768 KB

    prep_wx<<<dim3((H3_ + 255) / 256), 256, 0, stream>>>(dk, db, K, gb, wx, cc);
    pack_Rf8<<<dim3(384), 256, 0, stream>>>(R, Rp);

    gru_f8<<<dim3(256), dim3(1024), 0, stream>>>(
        x, km, Rp, wx, cc, gb + H3_, out, out1);
}

// Round 7
// 3108.245 us; speedup vs baseline: 1.7112x; 1.7112x over previous
//
#include <hip/hip_runtime.h>
#include <hip/hip_bf16.h>
#include <hip/hip_fp8.h>
#include <math.h>

// Encoder GRU, B=8192 T=256 H=512 — sync-free state-resident, v10.
// v8 protocol (per-wave flags, HW fp8 cvt, dbuf state, setprio) with the
// B stream moved to an LDS ring fed by global_load_lds (T3/T4):
//   - ring: 2 slots x 16 waves x 3 KB (96 KB LDS); slot = phase&1
//   - per phase: vmcnt(3) [next phase's 3 loads stay in flight] ->
//     asm ds_read_b128 x3 (B) + ds_read_b64 x2 (A) -> lgkmcnt(0) +
//     sched_barrier(0) -> refill slot for phase+2 (wraps across the step,
//     flying through the epilogue) -> 12 MFMA.
// Why: v8/v9 showed the B-stream is bytes-in-flight limited; a VGPR ring
// cannot deepen (128-reg/wave budget at 16 waves/CU: 64 AGPR + 64 VGPR is
// full — v9's +24 VGPRs spilled, FETCH 4.7 GB). global_load_lds keeps
// ~50-100 KB/CU in flight with ZERO result VGPRs. All hot-loop LDS reads
// are inline asm so the compiler can't couple them to the staging with
// conservative vmcnt(0) drains. kc order unchanged -> identical numerics.
// d_in: x(B,T), kmforenc(T), dense_kernel(1,H), dense_bias(H),
//       gru_kernel(H,3H), gru_recurrent(H,3H), gru_bias(2,3H)

constexpr int B_  = 8192;
constexpr int T_  = 256;
constexpr int H_  = 512;
constexpr int H3_ = 1536;
constexpr size_t BH = (size_t)B_ * H_;
constexpr int ROWS = 32;

// LDS layout (byte offsets inside the single shared block)
constexpr int ST0  = 0;          // state plane 0 (16 KB, swizzled fp8)
constexpr int ST1  = 16384;      // state plane 1
constexpr int RING = 32768;      // B ring: 2 x 16 waves x 3 KB = 96 KB
constexpr int SLOT = 49152;      // ring slot stride
constexpr int WSTR = 3072;       // per-wave stride within a slot
constexpr int RKM  = 131072;     // 256 f32 reciprocal divisors
constexpr int FLG  = 132096;     // 16 int flags
constexpr int LDSZ = 132160;

typedef float f32x4 __attribute__((ext_vector_type(4)));
typedef long  lx2   __attribute__((ext_vector_type(2)));

__device__ __forceinline__ unsigned char f2e4m3(float f) {
    __hip_fp8_e4m3 v(f); return v.__x;
}
// swizzled byte offset into one fp8 state plane [32 rows][512 cols]
__device__ __forceinline__ int swz(int row, int col) {
    return (row * 512 + col) ^ ((row & 15) << 3);
}
__device__ __forceinline__ float fast_sigmoid(float v) {
    return __builtin_amdgcn_rcpf(1.f + __expf(-v));
}
__device__ __forceinline__ float fast_tanh(float v) {
    float a = fabsf(v);
    float e = __expf(-2.f * a);
    float t = (1.f - e) * __builtin_amdgcn_rcpf(1.f + e);
    return copysignf(t, v);
}
// async 16B/lane global->LDS; lds_off is a raw LDS byte offset (wave-uniform)
__device__ __forceinline__ void gload16(const unsigned long long* g,
                                        unsigned lds_off) {
    __builtin_amdgcn_global_load_lds(
        (const __attribute__((address_space(1))) unsigned int*)g,
        (__attribute__((address_space(3))) unsigned int*)(unsigned long long)lds_off,
        16, 0, 0);
}

// wx[j] = sum_h dense_kernel[h]*gru_kernel[h,j]
// cc[j] = sum_h dense_bias[h]*gru_kernel[h,j] + gru_bias[0][j]
__global__ void prep_wx(const float* __restrict__ dk,
                        const float* __restrict__ db,
                        const float* __restrict__ K,
                        const float* __restrict__ gb,
                        float* __restrict__ wx,
                        float* __restrict__ cc) {
    int j = blockIdx.x * blockDim.x + threadIdx.x;
    if (j >= H3_) return;
    float a = 0.f, c = 0.f;
    for (int h = 0; h < H_; ++h) {
        float kv = K[(size_t)h * H3_ + j];
        a = fmaf(dk[h], kv, a);
        c = fmaf(db[h], kv, c);
    }
    wx[j] = a;
    cc[j] = c + gb[j];
}

// Pack R (H x 3H row-major) into per-(kc,w) fragment-PAIR blocks: pair block
// (kc,w,p) = 128 ulongs; lane L holds ulongs [2L,2L+1] = frag f=2p,2p+1.
//   frag f: n = g*512 + w*32 + q*16 + (lane&15), k = kc*32 + 8*(lane>>4)+e,
//   g=f>>1, q=f&1. Layout is linear-in-lane (byte 16L for lane L) -> exactly
//   the global_load_lds destination pattern.
__global__ void pack_Rf8(const float* __restrict__ R,
                         unsigned long long* __restrict__ Rp) {
    int idx  = blockIdx.x * 256 + threadIdx.x;    // < 98304
    int lane = idx & 63;
    int fi   = idx >> 6;                          // 0..1535
    int f    = fi % 6;
    int rest = fi / 6;                            // kc*16 + w
    int g    = f >> 1, q = f & 1;
    int w    = rest & 15;
    int n    = g * 512 + w * 32 + q * 16 + (lane & 15);
    int kb   = (rest >> 4) * 32 + 8 * (lane >> 4);
    unsigned long long v = 0;
    #pragma unroll
    for (int e = 0; e < 8; ++e)
        v |= (unsigned long long)f2e4m3(R[(size_t)(kb + e) * H3_ + n]) << (8 * e);
    Rp[(size_t)(rest * 3 + g) * 128 + 2 * lane + q] = v;
}

__global__ __launch_bounds__(1024, 4) void gru_f8(
    const float* __restrict__ x, const float* __restrict__ km,
    const unsigned long long* __restrict__ Rp,
    const float* __restrict__ wx, const float* __restrict__ cc,
    const float* __restrict__ b1,
    float* __restrict__ out0, float* __restrict__ out1)
{
    __shared__ __align__(16) char lds[LDSZ];

    const int tid  = threadIdx.x;
    const int lane = tid & 63;
    const int w    = tid >> 6;                    // wave 0..15 -> cols [w*32,+32)
    const int l15  = lane & 15;
    const int lh   = lane >> 4;                   // 0..3
    const int row0 = blockIdx.x * ROWS;
    const bool odd1 = (l15 & 1) != 0;
    const bool odd2 = (l15 & 2) != 0;
    // LDS base as raw offset (shared aperture is 4GB-aligned -> low32 = offset)
    const unsigned LB = (unsigned)(unsigned long long)(void*)lds;

    volatile int* vflag = (volatile int*)(lds + FLG);
    float* rkmp = (float*)(lds + RKM);

    if (tid < T_) rkmp[tid] = 1.f / km[tid];
    if (tid < 16) ((int*)(lds + FLG))[tid] = 0;

    // per-thread gate constants (loop-invariant)
    const int jcq[2] = { w * 32 + l15, w * 32 + 16 + l15 };
    float wxz[2], wxr[2], wxh[2], czc[2], crc[2], cch[2], b1h[2];
    #pragma unroll
    for (int q = 0; q < 2; ++q) {
        int jc = jcq[q];
        wxz[q] = wx[jc];  wxr[q] = wx[512 + jc];  wxh[q] = wx[1024 + jc];
        czc[q] = cc[jc]        + b1[jc];
        crc[q] = cc[512 + jc]  + b1[512 + jc];
        cch[q] = cc[1024 + jc];
        b1h[q] = b1[1024 + jc];
    }

    float hprev[2][2][4];                         // [q][mi][rr] fp32 carry
    #pragma unroll
    for (int q = 0; q < 2; ++q)
        #pragma unroll
        for (int mi = 0; mi < 2; ++mi)
            #pragma unroll
            for (int rr = 0; rr < 4; ++rr) hprev[q][mi][rr] = 0.f;

    // B stream source: pair block stride 128 ulongs, kc stride 6144 ulongs;
    // wb is the per-lane address (lane L -> byte 16L of each pair block).
    const unsigned long long* wb = Rp + (size_t)w * 384 + 2 * lane;

    __syncthreads();   // rkm + flags init visible (only barrier in kernel)

    // prologue: stage t=1 phases 0,1 into ring slots 0,1
    #pragma unroll
    for (int p = 0; p < 3; ++p) {
        gload16(wb + p * 128,        LB + RING + 0 * SLOT + w * WSTR + p * 1024);
        gload16(wb + 6144 + p * 128, LB + RING + 1 * SLOT + w * WSTR + p * 1024);
    }

    #pragma unroll 1
    for (int t = 0; t < T_; ++t) {
        const int stR = ST0 + (t & 1) * 16384;             // old state plane
        const int stW = ST0 + ((t & 1) ^ 1) * 16384;       // new state plane

        f32x4 acc[6][2];
        #pragma unroll
        for (int f = 0; f < 6; ++f) {
            acc[f][0] = (f32x4){0.f, 0.f, 0.f, 0.f};
            acc[f][1] = (f32x4){0.f, 0.f, 0.f, 0.f};
        }

        if (t > 0) {
            #pragma unroll 1
            for (int ph = 0; ph < 16; ++ph) {
                // producer gate for state cols [ph*32, ph*32+32)
                while (vflag[ph] < t) __builtin_amdgcn_s_sleep(1);
                asm volatile("" ::: "memory");
                // phase ph's 3 staged loads landed; next phase's stay in flight
                asm volatile("s_waitcnt vmcnt(3)" ::: "memory");
                const int sb    = LB + RING + (ph & 1) * SLOT + w * WSTR + 16 * lane;
                const int a0off = LB + stR + swz(l15,      ph * 32 + lh * 8);
                const int a1off = LB + stR + swz(l15 + 16, ph * 32 + lh * 8);
                lx2 b0, b1r, b2;
                long A0, A1;
                asm volatile("ds_read_b128 %0, %1"             : "=v"(b0)  : "v"(sb));
                asm volatile("ds_read_b128 %0, %1 offset:1024" : "=v"(b1r) : "v"(sb));
                asm volatile("ds_read_b128 %0, %1 offset:2048" : "=v"(b2)  : "v"(sb));
                asm volatile("ds_read_b64 %0, %1"  : "=v"(A0) : "v"(a0off));
                asm volatile("ds_read_b64 %0, %1"  : "=v"(A1) : "v"(a1off));
                asm volatile("s_waitcnt lgkmcnt(0)" ::: "memory");
                __builtin_amdgcn_sched_barrier(0);     // rule #18: pin MFMAs below
                // refill this slot for phase ph+2 (wraps into next step's
                // ph&1 at ph>=14 — those 6 loads fly through the epilogue)
                {
                    const unsigned long long* gsrc =
                        wb + (size_t)((ph + 2) & 15) * 6144;
                    const unsigned ldst = LB + RING + (ph & 1) * SLOT + w * WSTR;
                    gload16(gsrc,       ldst);
                    gload16(gsrc + 128, ldst + 1024);
                    gload16(gsrc + 256, ldst + 2048);
                }
                __builtin_amdgcn_s_setprio(1);
                {
                    const lx2 bb[3] = { b0, b1r, b2 };
                    #pragma unroll
                    for (int p = 0; p < 3; ++p) {
                        #pragma unroll
                        for (int jj = 0; jj < 2; ++jj) {
                            const int f = 2 * p + jj;
                            acc[f][0] = __builtin_amdgcn_mfma_f32_16x16x32_fp8_fp8(
                                A0, bb[p][jj], acc[f][0], 0, 0, 0);
                            acc[f][1] = __builtin_amdgcn_mfma_f32_16x16x32_fp8_fp8(
                                A1, bb[p][jj], acc[f][1], 0, 0, 0);
                        }
                    }
                }
                __builtin_amdgcn_s_setprio(0);
            }
        }

        // gates + state update; reads old plane (stR), writes new (stW).
        const float rk = rkmp[t];
        #pragma unroll
        for (int mi = 0; mi < 2; ++mi) {
            #pragma unroll
            for (int rr = 0; rr < 4; ++rr) {
                const int brow = mi * 16 + lh * 4 + rr;
                const float cb = ((t == 0)
                    ? x[(size_t)(row0 + brow) * T_]
                    : __builtin_amdgcn_cvt_f32_fp8(
                          (int)*(const unsigned char*)(lds + stR + swz(brow, t)),
                          0)) * rk;
                #pragma unroll
                for (int q = 0; q < 2; ++q) {
                    float z   = fast_sigmoid(fmaf(cb, wxz[q], czc[q])
                                             + acc[q][mi][rr]);
                    float r   = fast_sigmoid(fmaf(cb, wxr[q], crc[q])
                                             + acc[2 + q][mi][rr]);
                    float mhh = acc[4 + q][mi][rr] + b1h[q];
                    float hh  = fast_tanh(fmaf(r, mhh, fmaf(cb, wxh[q], cch[q])));
                    float hn  = fmaf(z, hprev[q][mi][rr] - hh, hh);
                    hprev[q][mi][rr] = hn;
                    // pack 4 consecutive cols (across l15 quads) into one dword:
                    // DPP xor1 swap -> HW cvt_pk (ordered pair) -> xor2 merge.
                    float nb = __shfl_xor(hn, 1);
                    float lo = odd1 ? nb : hn;
                    float hi = odd1 ? hn : nb;
                    unsigned int w16 = (unsigned int)
                        __builtin_amdgcn_cvt_pk_fp8_f32(lo, hi, 0, false);
                    unsigned int v16 = (unsigned int)__shfl_xor((int)w16, 2);
                    unsigned int w32 = (odd2 ? v16 : w16)
                                     | ((odd2 ? w16 : v16) << 16);
                    if ((l15 & 3) == 0)
                        *(unsigned int*)(lds + stW
                            + swz(brow, w * 32 + q * 16 + l15)) = w32;
                }
            }
        }

        // publish: all this wave's LDS reads/writes done, then raise flag.
        asm volatile("s_waitcnt lgkmcnt(0)" ::: "memory");
        if (lane == 0) vflag[w] = t + 1;
    }

    // drain tail staging before LDS dealloc / end of kernel
    asm volatile("s_waitcnt vmcnt(0)" ::: "memory");

    // final state from fp32 register carry -> both output halves
    #pragma unroll
    for (int q = 0; q < 2; ++q)
        #pragma unroll
        for (int mi = 0; mi < 2; ++mi)
            #pragma unroll
            for (int rr = 0; rr < 4; ++rr) {
                int brow = mi * 16 + lh * 4 + rr;
                size_t o = (size_t)(row0 + brow) * H_ + jcq[q];
                float v = hprev[q][mi][rr];
                out0[o] = v;
                out1[o] = v;
            }
}

extern "C" void kernel_launch(void* const* d_in, const int* in_sizes, int n_in,
                              void* d_out, int out_size, void* d_ws, size_t ws_size,
                              hipStream_t stream) {
    const float* x  = (const float*)d_in[0];
    const float* km = (const float*)d_in[1];
    const float* dk = (const float*)d_in[2];
    const float* db = (const float*)d_in[3];
    const float* K  = (const float*)d_in[4];
    const float* R  = (const float*)d_in[5];
    const float* gb = (const float*)d_in[6];

    float* out  = (float*)d_out;
    float* out1 = out + BH;

    float* wx = (float*)d_ws;                     // 1536 f
    float* cc = wx + H3_;                         // 1536 f
    unsigned long long* Rp = (unsigned long long*)(cc + H3_);   // 768 KB

    prep_wx<<<dim3((H3_ + 255) / 256), 256, 0, stream>>>(dk, db, K, gb, wx, cc);
    pack_Rf8<<<dim3(384), 256, 0, stream>>>(R, Rp);

    gru_f8<<<dim3(256), dim3(1024), 0, stream>>>(
        x, km, Rp, wx, cc, gb + H3_, out, out1);
}